// Round 9
// baseline (29.441 us; speedup 1.0000x reference)
//
#include <hip/hip_runtime.h>
#include <math.h>

#define DEVFN __device__ __forceinline__

typedef __attribute__((ext_vector_type(8))) _Float16 f16x8;
typedef __attribute__((ext_vector_type(4))) float f32x4;

DEVFN float shxor(float v, int m) { return __shfl_xor(v, m, 64); }

// ---------------------------------------------------------------------------
// Gate machinery (verified R1/R3/R4/R5).
// State layout: amplitude index a (8 bits) = lane*4 + k; wire w <-> bit 7-w.
// ---------------------------------------------------------------------------
template<int W>
DEVFN void rot_gate(int lane, float (&sr)[4], float (&si)[4], const float* u) {
  const float u00r=u[0], u00i=u[1], u01r=u[2], u01i=u[3];
  const float u10r=u[4], u10i=u[5], u11r=u[6], u11i=u[7];
  if constexpr (W <= 5) {
    constexpr int M = 1 << (5 - W);
    const bool hi = (lane & M) != 0;
    const float cmr = hi ? u11r : u00r, cmi = hi ? u11i : u00i;
    const float cor = hi ? u10r : u01r, coi = hi ? u10i : u01i;
    #pragma unroll
    for (int k = 0; k < 4; ++k) {
      float orr = shxor(sr[k], M);
      float oii = shxor(si[k], M);
      float nr = cmr*sr[k] - cmi*si[k] + cor*orr - coi*oii;
      float ni = cmr*si[k] + cmi*sr[k] + cor*oii + coi*orr;
      sr[k] = nr; si[k] = ni;
    }
  } else {
    constexpr int KB = (W == 6) ? 2 : 1;
    #pragma unroll
    for (int k0 = 0; k0 < 4; ++k0) {
      if ((k0 & KB) == 0) {
        const int k1 = k0 | KB;
        float ar = sr[k0], ai = si[k0];
        float br = sr[k1], bi = si[k1];
        sr[k0] = u00r*ar - u00i*ai + u01r*br - u01i*bi;
        si[k0] = u00r*ai + u00i*ar + u01r*bi + u01i*br;
        sr[k1] = u10r*ar - u10i*ai + u11r*br - u11i*bi;
        si[k1] = u10r*ai + u10i*ar + u11r*bi + u11i*br;
      }
    }
  }
}

template<int C, int T>
DEVFN void cnot_gate(int lane, float (&sr)[4], float (&si)[4]) {
  constexpr int PC = 7 - C, PT = 7 - T;
  if constexpr (PT >= 2) {
    constexpr int M = 1 << (PT - 2);
    #pragma unroll
    for (int k = 0; k < 4; ++k) {
      float orr = shxor(sr[k], M);
      float oii = shxor(si[k], M);
      bool ctrl;
      if constexpr (PC >= 2) ctrl = ((lane >> (PC - 2)) & 1) != 0;
      else                   ctrl = ((k >> PC) & 1) != 0;
      if (ctrl) { sr[k] = orr; si[k] = oii; }
    }
  } else {
    float tr[4], ti[4];
    #pragma unroll
    for (int k = 0; k < 4; ++k) { tr[k] = sr[k]; ti[k] = si[k]; }
    #pragma unroll
    for (int k = 0; k < 4; ++k) {
      bool ctrl;
      if constexpr (PC >= 2) ctrl = ((lane >> (PC - 2)) & 1) != 0;
      else                   ctrl = ((k >> PC) & 1) != 0;
      if (ctrl) { sr[k] = tr[k ^ (1 << PT)]; si[k] = ti[k ^ (1 << PT)]; }
    }
  }
}

// ---------------------------------------------------------------------------
// Prep (identical to validated R5/R7): blocks 0..255 simulate basis state
// e_col and scatter into per-wave MFMA fragment layout:
//   Bfrag[((ch*4 + q)*8 + ks)*512 + (kg*16 + cf)*8 + e]
// Block 256: folded LayerNorm/FC stats.
// ---------------------------------------------------------------------------
__global__ __launch_bounds__(64) void qsb_prep(
    const float* __restrict__ qw, const float* __restrict__ Wm,
    const float* __restrict__ bias,
    _Float16* __restrict__ Bfrag, float* __restrict__ stats) {
  __shared__ float uL[16 * 8];
  int bid = blockIdx.x;
  int lane = threadIdx.x;
  if (bid < 256) {
    if (lane < 16) {
      int l = lane >> 3, i = lane & 7;
      float phi = qw[l*24 + i*3 + 0];
      float th  = qw[l*24 + i*3 + 1];
      float om  = qw[l*24 + i*3 + 2];
      float cth = cosf(0.5f*th), sth = sinf(0.5f*th);
      float ap = 0.5f*(phi+om), am = 0.5f*(phi-om);
      float cap = cosf(ap), sap = sinf(ap);
      float cam = cosf(am), sam = sinf(am);
      float* u = &uL[lane*8];
      u[0] =  cap*cth; u[1] = -sap*cth;
      u[2] = -cam*sth; u[3] = -sam*sth;
      u[4] =  cam*sth; u[5] = -sam*sth;
      u[6] =  cap*cth; u[7] =  sap*cth;
    }
    __syncthreads();
    int col = bid;
    float sr[4], si[4];
    #pragma unroll
    for (int k = 0; k < 4; ++k) { sr[k] = (lane*4 + k == col) ? 1.f : 0.f; si[k] = 0.f; }
    rot_gate<0>(lane, sr, si, &uL[0*8]);
    rot_gate<1>(lane, sr, si, &uL[1*8]);
    rot_gate<2>(lane, sr, si, &uL[2*8]);
    rot_gate<3>(lane, sr, si, &uL[3*8]);
    rot_gate<4>(lane, sr, si, &uL[4*8]);
    rot_gate<5>(lane, sr, si, &uL[5*8]);
    rot_gate<6>(lane, sr, si, &uL[6*8]);
    rot_gate<7>(lane, sr, si, &uL[7*8]);
    cnot_gate<0,1>(lane, sr, si);
    cnot_gate<1,2>(lane, sr, si);
    cnot_gate<2,3>(lane, sr, si);
    cnot_gate<3,4>(lane, sr, si);
    cnot_gate<4,5>(lane, sr, si);
    cnot_gate<5,6>(lane, sr, si);
    cnot_gate<6,7>(lane, sr, si);
    cnot_gate<7,0>(lane, sr, si);
    rot_gate<0>(lane, sr, si, &uL[(8+0)*8]);
    rot_gate<1>(lane, sr, si, &uL[(8+1)*8]);
    rot_gate<2>(lane, sr, si, &uL[(8+2)*8]);
    rot_gate<3>(lane, sr, si, &uL[(8+3)*8]);
    rot_gate<4>(lane, sr, si, &uL[(8+4)*8]);
    rot_gate<5>(lane, sr, si, &uL[(8+5)*8]);
    rot_gate<6>(lane, sr, si, &uL[(8+6)*8]);
    rot_gate<7>(lane, sr, si, &uL[(8+7)*8]);
    cnot_gate<0,2>(lane, sr, si);
    cnot_gate<1,3>(lane, sr, si);
    cnot_gate<2,4>(lane, sr, si);
    cnot_gate<3,5>(lane, sr, si);
    cnot_gate<4,6>(lane, sr, si);
    cnot_gate<5,7>(lane, sr, si);
    cnot_gate<6,0>(lane, sr, si);
    cnot_gate<7,1>(lane, sr, si);
    const int ks = col >> 5, kg = (col >> 3) & 3, e = col & 7;
    #pragma unroll
    for (int k = 0; k < 4; ++k) {
      int a = lane*4 + k;
      int ch = a >> 5, nf = (a >> 4) & 1, cf = a & 15;
      int pos = (kg*16 + cf)*8 + e;
      Bfrag[((ch*4 + nf    )*8 + ks)*512 + pos] = (_Float16)sr[k];
      Bfrag[((ch*4 + 2 + nf)*8 + ks)*512 + pos] = (_Float16)si[k];
    }
  } else {
    int t = lane;
    {
      int i = t >> 3, j = t & 7;
      float s = 0.f;
      for (int c = 0; c < 64; ++c) s += Wm[i*64 + c] * Wm[j*64 + c];
      stats[16 + t] = s * 0.015625f;
    }
    if (t < 8) {
      float s = 0.f, sb = 0.f;
      for (int c = 0; c < 64; ++c) { float w = Wm[t*64 + c]; s += w; sb += w * bias[c]; }
      stats[t]     = s * 0.015625f;
      stats[8 + t] = 2.f * sb * 0.015625f;
    }
    if (t == 0) {
      float s = 0.f, s2 = 0.f;
      for (int c = 0; c < 64; ++c) { s += bias[c]; s2 += bias[c]*bias[c]; }
      stats[80] = s * 0.015625f;
      stats[81] = s2 * 0.015625f;
    }
  }
}

// ---------------------------------------------------------------------------
// Main: 32 rows/block, 256 threads (4 waves), grid = B/32 = 1024 blocks.
// Wave wid handles chunks {2*wid, 2*wid+1} (16 half-steps, rotating B banks).
// Chunk epilogue: probs -> wave-private LDS transpose -> S-MFMA -> zpart.
// Phase 4/5: combine chunks + folded LN stats.
// Phase 6 (NEW): FC via one MFMA per 16-row half; wave wid owns col-tile
//   wid*16..wid*16+16. A-frag = W cols (global), B-frag = z rows (2 b128 LDS
//   reads), D = h in standard C-layout -> LN + exact GELU -> store.
// Amp bits: b7b6b5 = chunk, b4 = nf, b3..b0 = cf; wire w <-> bit 7-w.
// ---------------------------------------------------------------------------
__global__ __launch_bounds__(256, 4) void qsb_main(
    const float* __restrict__ pca, const _Float16* __restrict__ Bfrag,
    const float* __restrict__ statsG,
    const float* __restrict__ Wm, const float* __restrict__ bias,
    const float* __restrict__ gamma, const float* __restrict__ beta,
    float* __restrict__ out, int B) {
  // A3: element (row,k): ((ks*2 + m)*16 + cf)*32 + (kg^(ks&3))*8 + e  (16 KB)
  __shared__ __align__(16) _Float16 A3[8192];
  __shared__ __align__(16) _Float16 YL[4 * 1280];  // per-wave Y, stride 40 (10 KB)
  __shared__ float zpart[2304];   // [ch=8][row=32][9], slots 0..5 used (9 KB)
  __shared__ float zrow[256];     // [row=32][8]
  __shared__ float musig[64];     // [row=32][2]
  __shared__ float statsL[82];

  const int tid = threadIdx.x;
  const int wid = tid >> 6, lane = tid & 63;
  const int cfrag = lane & 15, kgrp = lane >> 4;
  const int r0 = blockIdx.x * 32;

  // ---- phase 0: preloads ----
  if (tid < 82) statsL[tid] = statsG[tid];

  // ---- sign fragment for the S-MFMA (B-frag: col=cfrag, k=kgrp*8+e) ----
  f16x8 sfrag;
  #pragma unroll
  for (int e = 0; e < 8; ++e) {
    float v;
    if      (cfrag == 0) v = 1.f;                        // T (chunk total)
    else if (cfrag == 1) v = (kgrp & 2) ? -1.f : 1.f;    // wire 3 (a bit4)
    else if (cfrag == 2) v = (kgrp & 1) ? -1.f : 1.f;    // wire 4 (a bit3)
    else if (cfrag == 3) v = (e & 4)    ? -1.f : 1.f;    // wire 5 (a bit2)
    else if (cfrag == 4) v = (e & 2)    ? -1.f : 1.f;    // wire 6 (a bit1)
    else if (cfrag == 5) v = (e & 1)    ? -1.f : 1.f;    // wire 7 (a bit0)
    else v = 0.f;
    sfrag[e] = (_Float16)v;
  }

  // ---- phase 1: A build (8 threads/row, 32 k each), fast trig ----
  {
    const int rl = tid >> 3, tq = tid & 7;
    const int r = r0 + rl;
    float cv[8], sv[8];
    #pragma unroll
    for (int w = 0; w < 8; ++w) { cv[w] = 1.f; sv[w] = 0.f; }
    if (r < B) {
      #pragma unroll
      for (int w = 0; w < 8; ++w) {
        float x = pca[r*8 + w];
        float sg = __builtin_amdgcn_rcpf(1.f + __expf(-x));
        float ang = 1.5707963267948966f * sg;
        cv[w] = __cosf(ang); sv[w] = __sinf(ang);
      }
    }
    float base = ((tq & 4) ? sv[0] : cv[0]) * ((tq & 2) ? sv[1] : cv[1])
               * ((tq & 1) ? sv[2] : cv[2]);
    float arr[32];
    arr[0] = base;
    #pragma unroll
    for (int p = 0; p < 5; ++p) {
      const int w = 7 - p;
      const int sz = 1 << p;
      #pragma unroll
      for (int i = 0; i < (1 << p); ++i) {
        arr[i + sz] = arr[i] * sv[w];
        arr[i]      = arr[i] * cv[w];
      }
    }
    _Float16* dstBase = &A3[((tq*2 + (rl >> 4))*16 + (rl & 15))*32];
    #pragma unroll
    for (int ib = 0; ib < 4; ++ib) {
      f16x8 v;
      #pragma unroll
      for (int j = 0; j < 8; ++j) v[j] = (_Float16)arr[ib*8 + j];
      *(f16x8*)(dstBase + (ib ^ (tq & 3))*8) = v;
    }
  }
  __syncthreads();   // barrier 1: A3 ready

  // ---- phases 2+3: 16-half-step pipelined GEMM + per-chunk epilogue ----
  _Float16* Yw = &YL[wid * 1280];
  const _Float16* BwBase = Bfrag + (size_t)(wid*2) * 16384 + lane*8;

  f32x4 acc[2][4];
  #pragma unroll
  for (int m = 0; m < 2; ++m)
    #pragma unroll
    for (int q = 0; q < 4; ++q) acc[m][q] = (f32x4){0.f, 0.f, 0.f, 0.f};

  f16x8 bk[3][4];   // rotating banks; all indices compile-time after unroll
  #pragma unroll
  for (int q = 0; q < 4; ++q) bk[0][q] = *(const f16x8*)(BwBase + 0*512 + q*4096);
  #pragma unroll
  for (int q = 0; q < 4; ++q) bk[1][q] = *(const f16x8*)(BwBase + 1*512 + q*4096);

  #pragma unroll
  for (int s = 0; s < 16; ++s) {
    const int ks = s & 7;
    const int bi = s % 3;
    if (s + 2 < 16) {
      const int bj = (s + 2) % 3;
      const int c2 = (s + 2) >> 3, ks2 = (s + 2) & 7;
      const _Float16* p2 = BwBase + c2*16384 + ks2*512;
      #pragma unroll
      for (int q = 0; q < 4; ++q) bk[bj][q] = *(const f16x8*)(p2 + q*4096);
    }
    {
      f16x8 af0 = *(const f16x8*)&A3[((ks*2 + 0)*16 + cfrag)*32 + (kgrp ^ (ks & 3))*8];
      f16x8 af1 = *(const f16x8*)&A3[((ks*2 + 1)*16 + cfrag)*32 + (kgrp ^ (ks & 3))*8];
      #pragma unroll
      for (int q = 0; q < 4; ++q) {
        acc[0][q] = __builtin_amdgcn_mfma_f32_16x16x32_f16(af0, bk[bi][q], acc[0][q], 0, 0, 0);
        acc[1][q] = __builtin_amdgcn_mfma_f32_16x16x32_f16(af1, bk[bi][q], acc[1][q], 0, 0, 0);
      }
    }
    if (ks == 7) {
      const int ch = wid*2 + (s >> 3);
      #pragma unroll
      for (int m = 0; m < 2; ++m) {
        #pragma unroll
        for (int nf = 0; nf < 2; ++nf) {
          #pragma unroll
          for (int j = 0; j < 4; ++j) {
            float re = acc[m][nf][j], im = acc[m][2 + nf][j];
            float p = re*re + im*im;
            Yw[m*640 + (kgrp*4 + j)*40 + nf*16 + cfrag] = (_Float16)p;
          }
        }
      }
      #pragma unroll
      for (int m = 0; m < 2; ++m) {
        f16x8 yfrag = *(const f16x8*)&Yw[m*640 + (lane & 15)*40 + kgrp*8];
        f32x4 d = __builtin_amdgcn_mfma_f32_16x16x32_f16(yfrag, sfrag, (f32x4){0.f,0.f,0.f,0.f}, 0, 0, 0);
        if (cfrag < 6) {
          #pragma unroll
          for (int j = 0; j < 4; ++j)
            zpart[(ch*32 + m*16 + kgrp*4 + j)*9 + cfrag] = d[j];
        }
      }
      #pragma unroll
      for (int m = 0; m < 2; ++m)
        #pragma unroll
        for (int q = 0; q < 4; ++q) acc[m][q] = (f32x4){0.f, 0.f, 0.f, 0.f};
    }
  }
  __syncthreads();   // barrier 2: zpart ready

  // ---- phase 4+5: combine chunks + LN stats (thread=(row,wire)) ----
  {
    const int row = tid >> 3, w = tid & 7;
    const int slot = (w < 3) ? 0 : (w - 2);
    const int sm = (w == 0) ? 4 : (w == 1) ? 2 : (w == 2) ? 1 : 0;
    float z = 0.f;
    #pragma unroll
    for (int ch = 0; ch < 8; ++ch) {
      float v = zpart[(ch*32 + row)*9 + slot];
      z += (ch & sm) ? -v : v;
    }
    zrow[row*8 + w] = z;
    // same wave wrote all 8 slots of this row -> in-order DS, read back
    f32x4 zlo = *(const f32x4*)&zrow[row*8];
    f32x4 zhi = *(const f32x4*)&zrow[row*8 + 4];
    float zj[8] = {zlo[0], zlo[1], zlo[2], zlo[3], zhi[0], zhi[1], zhi[2], zhi[3]};
    float qi = statsL[8 + w];
    #pragma unroll
    for (int j = 0; j < 8; ++j) qi += statsL[16 + w*8 + j] * zj[j];
    float e2p = zj[w] * qi;
    float mup = statsL[w] * zj[w];
    e2p += shxor(e2p, 1); e2p += shxor(e2p, 2); e2p += shxor(e2p, 4);
    mup += shxor(mup, 1); mup += shxor(mup, 2); mup += shxor(mup, 4);
    if (w == 0) {
      float mu = mup + statsL[80];
      float e2 = e2p + statsL[81];
      float var = e2 - mu*mu;
      musig[row*2]     = mu;
      musig[row*2 + 1] = rsqrtf(fmaxf(var, 0.f) + 1e-5f);
    }
  }
  __syncthreads();   // barrier 3: zrow + musig ready (phase 6 reads cross-wave)

  // ---- phase 6: FC via MFMA (wave wid -> col-tile wid*16..+16), LN + GELU ----
  {
    // A-frag: A[x=col][k] = W[k][wid*16+x] for k<8 (kg==0 lanes), else 0
    f16x8 wfrag;
    #pragma unroll
    for (int e = 0; e < 8; ++e) {
      float v = Wm[e*64 + wid*16 + cfrag];
      wfrag[e] = (_Float16)((kgrp == 0) ? v : 0.f);
    }
    #pragma unroll
    for (int m = 0; m < 2; ++m) {
      const int row = m*16 + cfrag;              // batch row within block
      // B-frag: B[k][y=row] = z[row][k] for k<8 (kg==0 lanes), else 0
      f32x4 zlo = *(const f32x4*)&zrow[row*8];
      f32x4 zhi = *(const f32x4*)&zrow[row*8 + 4];
      f16x8 zfrag;
      #pragma unroll
      for (int e = 0; e < 4; ++e) {
        zfrag[e]     = (_Float16)((kgrp == 0) ? zlo[e] : 0.f);
        zfrag[4 + e] = (_Float16)((kgrp == 0) ? zhi[e] : 0.f);
      }
      f32x4 d = __builtin_amdgcn_mfma_f32_16x16x32_f16(wfrag, zfrag,
                                                       (f32x4){0.f,0.f,0.f,0.f}, 0, 0, 0);
      // D: lane (cfrag,kgrp) reg j -> h[batchrow=row][col=wid*16+kgrp*4+j]
      float mu  = musig[row*2];
      float isg = musig[row*2 + 1];
      const int gr = r0 + row;
      #pragma unroll
      for (int j = 0; j < 4; ++j) {
        const int col = wid*16 + kgrp*4 + j;
        float h  = d[j] + bias[col];
        float hn = (h - mu) * isg * gamma[col] + beta[col];
        float ge = 0.5f * hn * (1.f + erff(hn * 0.70710678118654752f));
        if (gr < B) out[gr*64 + col] = ge;
      }
    }
  }
}

extern "C" void kernel_launch(void* const* d_in, const int* in_sizes, int n_in,
                              void* d_out, int out_size, void* d_ws, size_t ws_size,
                              hipStream_t stream) {
  const float* pca   = (const float*)d_in[0];
  const float* qw    = (const float*)d_in[1];
  const float* Wm    = (const float*)d_in[2];
  const float* bias  = (const float*)d_in[3];
  const float* gamma = (const float*)d_in[4];
  const float* beta  = (const float*)d_in[5];
  float* out = (float*)d_out;

  _Float16* Bfrag = (_Float16*)d_ws;                   // 512*256*2 = 256 KiB
  float* stats = (float*)((char*)d_ws + 512*256*2);    // 82 floats

  int B = in_sizes[0] / 8;

  hipLaunchKernelGGL(qsb_prep, dim3(257), dim3(64), 0, stream, qw, Wm, bias, Bfrag, stats);
  int blocks = (B + 31) / 32;
  hipLaunchKernelGGL(qsb_main, dim3(blocks), dim3(256), 0, stream,
                     pca, Bfrag, stats, Wm, bias, gamma, beta, out, B);
}

// Round 10
// 29.270 us; speedup vs baseline: 1.0058x; 1.0058x over previous
//
#include <hip/hip_runtime.h>
#include <math.h>

#define DEVFN __device__ __forceinline__

typedef __attribute__((ext_vector_type(8))) _Float16 f16x8;
typedef __attribute__((ext_vector_type(4))) float f32x4;

DEVFN float shxor(float v, int m) { return __shfl_xor(v, m, 64); }

// ---------------------------------------------------------------------------
// Gate machinery (verified R1/R3/R4/R5).
// State layout: amplitude index a (8 bits) = lane*4 + k; wire w <-> bit 7-w.
// ---------------------------------------------------------------------------
template<int W>
DEVFN void rot_gate(int lane, float (&sr)[4], float (&si)[4], const float* u) {
  const float u00r=u[0], u00i=u[1], u01r=u[2], u01i=u[3];
  const float u10r=u[4], u10i=u[5], u11r=u[6], u11i=u[7];
  if constexpr (W <= 5) {
    constexpr int M = 1 << (5 - W);
    const bool hi = (lane & M) != 0;
    const float cmr = hi ? u11r : u00r, cmi = hi ? u11i : u00i;
    const float cor = hi ? u10r : u01r, coi = hi ? u10i : u01i;
    #pragma unroll
    for (int k = 0; k < 4; ++k) {
      float orr = shxor(sr[k], M);
      float oii = shxor(si[k], M);
      float nr = cmr*sr[k] - cmi*si[k] + cor*orr - coi*oii;
      float ni = cmr*si[k] + cmi*sr[k] + cor*oii + coi*orr;
      sr[k] = nr; si[k] = ni;
    }
  } else {
    constexpr int KB = (W == 6) ? 2 : 1;
    #pragma unroll
    for (int k0 = 0; k0 < 4; ++k0) {
      if ((k0 & KB) == 0) {
        const int k1 = k0 | KB;
        float ar = sr[k0], ai = si[k0];
        float br = sr[k1], bi = si[k1];
        sr[k0] = u00r*ar - u00i*ai + u01r*br - u01i*bi;
        si[k0] = u00r*ai + u00i*ar + u01r*bi + u01i*br;
        sr[k1] = u10r*ar - u10i*ai + u11r*br - u11i*bi;
        si[k1] = u10r*ai + u10i*ar + u11r*bi + u11i*br;
      }
    }
  }
}

template<int C, int T>
DEVFN void cnot_gate(int lane, float (&sr)[4], float (&si)[4]) {
  constexpr int PC = 7 - C, PT = 7 - T;
  if constexpr (PT >= 2) {
    constexpr int M = 1 << (PT - 2);
    #pragma unroll
    for (int k = 0; k < 4; ++k) {
      float orr = shxor(sr[k], M);
      float oii = shxor(si[k], M);
      bool ctrl;
      if constexpr (PC >= 2) ctrl = ((lane >> (PC - 2)) & 1) != 0;
      else                   ctrl = ((k >> PC) & 1) != 0;
      if (ctrl) { sr[k] = orr; si[k] = oii; }
    }
  } else {
    float tr[4], ti[4];
    #pragma unroll
    for (int k = 0; k < 4; ++k) { tr[k] = sr[k]; ti[k] = si[k]; }
    #pragma unroll
    for (int k = 0; k < 4; ++k) {
      bool ctrl;
      if constexpr (PC >= 2) ctrl = ((lane >> (PC - 2)) & 1) != 0;
      else                   ctrl = ((k >> PC) & 1) != 0;
      if (ctrl) { sr[k] = tr[k ^ (1 << PT)]; si[k] = ti[k ^ (1 << PT)]; }
    }
  }
}

// ---------------------------------------------------------------------------
// Prep (identical to validated R5/R7): blocks 0..255 simulate basis state
// e_col and scatter into per-wave MFMA fragment layout:
//   Bfrag[((ch*4 + q)*8 + ks)*512 + (kg*16 + cf)*8 + e]
// Block 256: folded LayerNorm/FC stats.
// ---------------------------------------------------------------------------
__global__ __launch_bounds__(64) void qsb_prep(
    const float* __restrict__ qw, const float* __restrict__ Wm,
    const float* __restrict__ bias,
    _Float16* __restrict__ Bfrag, float* __restrict__ stats) {
  __shared__ float uL[16 * 8];
  int bid = blockIdx.x;
  int lane = threadIdx.x;
  if (bid < 256) {
    if (lane < 16) {
      int l = lane >> 3, i = lane & 7;
      float phi = qw[l*24 + i*3 + 0];
      float th  = qw[l*24 + i*3 + 1];
      float om  = qw[l*24 + i*3 + 2];
      float cth = cosf(0.5f*th), sth = sinf(0.5f*th);
      float ap = 0.5f*(phi+om), am = 0.5f*(phi-om);
      float cap = cosf(ap), sap = sinf(ap);
      float cam = cosf(am), sam = sinf(am);
      float* u = &uL[lane*8];
      u[0] =  cap*cth; u[1] = -sap*cth;
      u[2] = -cam*sth; u[3] = -sam*sth;
      u[4] =  cam*sth; u[5] = -sam*sth;
      u[6] =  cap*cth; u[7] =  sap*cth;
    }
    __syncthreads();
    int col = bid;
    float sr[4], si[4];
    #pragma unroll
    for (int k = 0; k < 4; ++k) { sr[k] = (lane*4 + k == col) ? 1.f : 0.f; si[k] = 0.f; }
    rot_gate<0>(lane, sr, si, &uL[0*8]);
    rot_gate<1>(lane, sr, si, &uL[1*8]);
    rot_gate<2>(lane, sr, si, &uL[2*8]);
    rot_gate<3>(lane, sr, si, &uL[3*8]);
    rot_gate<4>(lane, sr, si, &uL[4*8]);
    rot_gate<5>(lane, sr, si, &uL[5*8]);
    rot_gate<6>(lane, sr, si, &uL[6*8]);
    rot_gate<7>(lane, sr, si, &uL[7*8]);
    cnot_gate<0,1>(lane, sr, si);
    cnot_gate<1,2>(lane, sr, si);
    cnot_gate<2,3>(lane, sr, si);
    cnot_gate<3,4>(lane, sr, si);
    cnot_gate<4,5>(lane, sr, si);
    cnot_gate<5,6>(lane, sr, si);
    cnot_gate<6,7>(lane, sr, si);
    cnot_gate<7,0>(lane, sr, si);
    rot_gate<0>(lane, sr, si, &uL[(8+0)*8]);
    rot_gate<1>(lane, sr, si, &uL[(8+1)*8]);
    rot_gate<2>(lane, sr, si, &uL[(8+2)*8]);
    rot_gate<3>(lane, sr, si, &uL[(8+3)*8]);
    rot_gate<4>(lane, sr, si, &uL[(8+4)*8]);
    rot_gate<5>(lane, sr, si, &uL[(8+5)*8]);
    rot_gate<6>(lane, sr, si, &uL[(8+6)*8]);
    rot_gate<7>(lane, sr, si, &uL[(8+7)*8]);
    cnot_gate<0,2>(lane, sr, si);
    cnot_gate<1,3>(lane, sr, si);
    cnot_gate<2,4>(lane, sr, si);
    cnot_gate<3,5>(lane, sr, si);
    cnot_gate<4,6>(lane, sr, si);
    cnot_gate<5,7>(lane, sr, si);
    cnot_gate<6,0>(lane, sr, si);
    cnot_gate<7,1>(lane, sr, si);
    const int ks = col >> 5, kg = (col >> 3) & 3, e = col & 7;
    #pragma unroll
    for (int k = 0; k < 4; ++k) {
      int a = lane*4 + k;
      int ch = a >> 5, nf = (a >> 4) & 1, cf = a & 15;
      int pos = (kg*16 + cf)*8 + e;
      Bfrag[((ch*4 + nf    )*8 + ks)*512 + pos] = (_Float16)sr[k];
      Bfrag[((ch*4 + 2 + nf)*8 + ks)*512 + pos] = (_Float16)si[k];
    }
  } else {
    int t = lane;
    {
      int i = t >> 3, j = t & 7;
      float s = 0.f;
      for (int c = 0; c < 64; ++c) s += Wm[i*64 + c] * Wm[j*64 + c];
      stats[16 + t] = s * 0.015625f;
    }
    if (t < 8) {
      float s = 0.f, sb = 0.f;
      for (int c = 0; c < 64; ++c) { float w = Wm[t*64 + c]; s += w; sb += w * bias[c]; }
      stats[t]     = s * 0.015625f;
      stats[8 + t] = 2.f * sb * 0.015625f;
    }
    if (t == 0) {
      float s = 0.f, s2 = 0.f;
      for (int c = 0; c < 64; ++c) { s += bias[c]; s2 += bias[c]*bias[c]; }
      stats[80] = s * 0.015625f;
      stats[81] = s2 * 0.015625f;
    }
  }
}

// ---------------------------------------------------------------------------
// Main: 64 rows/block (M=64), 256 threads (4 waves), grid = B/64 = 512 blocks.
// Wave wid handles chunks {2*wid, 2*wid+1} for ALL 64 rows (16 half-steps,
// rotating B banks). Per step: 4 m-tiles x 4 q = 16 MFMAs.
// A3 layout: element (row,k): ((ks*4 + m)*16 + cf)*32 + slot*8,
//   slot = kg ^ (ks&3) ^ ((cf>>1)&3); ks=k>>5, kg=(k>>3)&3, e=k&7,
//   m=row>>4, cf=row&15. (quarter-wave-tiling XOR -> conflict-free b128)
// Chunk epilogue: probs -> wave-private Y transpose -> S-MFMA -> zpart[ch][64][9].
// Phase 4/5 run per 32-row half (wave-local); phase 6 barrier-free (R8 form).
// Amp bits: b7b6b5 = chunk, b4 = nf, b3..b0 = cf; wire w <-> bit 7-w.
// ---------------------------------------------------------------------------
__global__ __launch_bounds__(256, 2) void qsb_main(
    const float* __restrict__ pca, const _Float16* __restrict__ Bfrag,
    const float* __restrict__ statsG,
    const float* __restrict__ Wm, const float* __restrict__ bias,
    const float* __restrict__ gamma, const float* __restrict__ beta,
    float* __restrict__ out, int B) {
  __shared__ __align__(16) _Float16 A3[16384];     // 64 rows x 256 k (32 KB)
  __shared__ __align__(16) _Float16 YL[4 * 2560];  // per-wave Y, 4m x 16 x 40 (20 KB)
  __shared__ float zpart[4608];   // [ch=8][row=64][9], slots 0..5 used (18 KB)
  __shared__ float zrow[512];     // [row=64][8]
  __shared__ float musig[128];    // [row=64][2]
  __shared__ float Wl[512];
  __shared__ float biasL[64], gammaL[64], betaL[64];
  __shared__ float statsL[82];

  const int tid = threadIdx.x;
  const int wid = tid >> 6, lane = tid & 63;
  const int cfrag = lane & 15, kgrp = lane >> 4;
  const int r0 = blockIdx.x * 64;

  // ---- phase 0: preloads ----
  #pragma unroll
  for (int i = tid; i < 512; i += 256) Wl[i] = Wm[i];
  if (tid >= 256 - 64) {
    int t = tid - (256 - 64);
    biasL[t] = bias[t]; gammaL[t] = gamma[t]; betaL[t] = beta[t];
  }
  if (tid < 82) statsL[tid] = statsG[tid];

  // ---- sign fragment for the S-MFMA (B-frag: col=cfrag, k=kgrp*8+e) ----
  f16x8 sfrag;
  #pragma unroll
  for (int e = 0; e < 8; ++e) {
    float v;
    if      (cfrag == 0) v = 1.f;                        // T (chunk total)
    else if (cfrag == 1) v = (kgrp & 2) ? -1.f : 1.f;    // wire 3 (a bit4)
    else if (cfrag == 2) v = (kgrp & 1) ? -1.f : 1.f;    // wire 4 (a bit3)
    else if (cfrag == 3) v = (e & 4)    ? -1.f : 1.f;    // wire 5 (a bit2)
    else if (cfrag == 4) v = (e & 2)    ? -1.f : 1.f;    // wire 6 (a bit1)
    else if (cfrag == 5) v = (e & 1)    ? -1.f : 1.f;    // wire 7 (a bit0)
    else v = 0.f;
    sfrag[e] = (_Float16)v;
  }

  // ---- phase 1: A build (4 threads/row, 64 k each), fast trig ----
  {
    const int rl = tid >> 2, tq = tid & 3;   // row-local 0..63, k-quarter 0..3
    const int r = r0 + rl;
    float cv[8], sv[8];
    #pragma unroll
    for (int w = 0; w < 8; ++w) { cv[w] = 1.f; sv[w] = 0.f; }
    if (r < B) {
      #pragma unroll
      for (int w = 0; w < 8; ++w) {
        float x = pca[r*8 + w];
        float sg = __builtin_amdgcn_rcpf(1.f + __expf(-x));
        float ang = 1.5707963267948966f * sg;
        cv[w] = __cosf(ang); sv[w] = __sinf(ang);
      }
    }
    // k high bits b7b6 = tq -> wires 0,1
    float base = ((tq & 2) ? sv[0] : cv[0]) * ((tq & 1) ? sv[1] : cv[1]);
    float arr[64];
    arr[0] = base;
    #pragma unroll
    for (int p = 0; p < 6; ++p) {            // bit p of i <-> wire 7-p
      const int w = 7 - p;
      const int sz = 1 << p;
      #pragma unroll
      for (int i = 0; i < (1 << p); ++i) {
        arr[i + sz] = arr[i] * sv[w];
        arr[i]      = arr[i] * cv[w];
      }
    }
    const int m = rl >> 4, cf = rl & 15;
    const int cfx = (cf >> 1) & 3;
    #pragma unroll
    for (int ib = 0; ib < 8; ++ib) {         // k = tq*64 + ib*8 + e
      const int ks = tq*2 + (ib >> 2);
      const int slot = (ib & 3) ^ (ks & 3) ^ cfx;
      f16x8 v;
      #pragma unroll
      for (int j = 0; j < 8; ++j) v[j] = (_Float16)arr[ib*8 + j];
      *(f16x8*)&A3[((ks*4 + m)*16 + cf)*32 + slot*8] = v;
    }
  }
  __syncthreads();   // barrier 1: A3 ready

  // ---- phases 2+3: 16-half-step pipelined GEMM + per-chunk epilogue ----
  _Float16* Yw = &YL[wid * 2560];
  const _Float16* BwBase = Bfrag + (size_t)(wid*2) * 16384 + lane*8;
  const int cfx = (cfrag >> 1) & 3;

  f32x4 acc[4][4];
  #pragma unroll
  for (int m = 0; m < 4; ++m)
    #pragma unroll
    for (int q = 0; q < 4; ++q) acc[m][q] = (f32x4){0.f, 0.f, 0.f, 0.f};

  f16x8 bk[3][4];   // rotating banks; all indices compile-time after unroll
  #pragma unroll
  for (int q = 0; q < 4; ++q) bk[0][q] = *(const f16x8*)(BwBase + 0*512 + q*4096);
  #pragma unroll
  for (int q = 0; q < 4; ++q) bk[1][q] = *(const f16x8*)(BwBase + 1*512 + q*4096);

  #pragma unroll
  for (int s = 0; s < 16; ++s) {
    const int ks = s & 7;
    const int bi = s % 3;
    if (s + 2 < 16) {
      const int bj = (s + 2) % 3;
      const int c2 = (s + 2) >> 3, ks2 = (s + 2) & 7;
      const _Float16* p2 = BwBase + c2*16384 + ks2*512;
      #pragma unroll
      for (int q = 0; q < 4; ++q) bk[bj][q] = *(const f16x8*)(p2 + q*4096);
    }
    {
      const int slot = (kgrp ^ (ks & 3) ^ cfx)*8;
      f16x8 af[4];
      #pragma unroll
      for (int m = 0; m < 4; ++m)
        af[m] = *(const f16x8*)&A3[((ks*4 + m)*16 + cfrag)*32 + slot];
      #pragma unroll
      for (int q = 0; q < 4; ++q) {
        #pragma unroll
        for (int m = 0; m < 4; ++m)
          acc[m][q] = __builtin_amdgcn_mfma_f32_16x16x32_f16(af[m], bk[bi][q], acc[m][q], 0, 0, 0);
      }
    }
    if (ks == 7) {
      const int ch = wid*2 + (s >> 3);
      #pragma unroll
      for (int m = 0; m < 4; ++m) {
        #pragma unroll
        for (int nf = 0; nf < 2; ++nf) {
          #pragma unroll
          for (int j = 0; j < 4; ++j) {
            float re = acc[m][nf][j], im = acc[m][2 + nf][j];
            float p = re*re + im*im;
            Yw[m*640 + (kgrp*4 + j)*40 + nf*16 + cfrag] = (_Float16)p;
          }
        }
      }
      #pragma unroll
      for (int m = 0; m < 4; ++m) {
        f16x8 yfrag = *(const f16x8*)&Yw[m*640 + (lane & 15)*40 + kgrp*8];
        f32x4 d = __builtin_amdgcn_mfma_f32_16x16x32_f16(yfrag, sfrag, (f32x4){0.f,0.f,0.f,0.f}, 0, 0, 0);
        if (cfrag < 6) {
          #pragma unroll
          for (int j = 0; j < 4; ++j)
            zpart[(ch*64 + m*16 + kgrp*4 + j)*9 + cfrag] = d[j];
        }
      }
      #pragma unroll
      for (int m = 0; m < 4; ++m)
        #pragma unroll
        for (int q = 0; q < 4; ++q) acc[m][q] = (f32x4){0.f, 0.f, 0.f, 0.f};
    }
  }
  __syncthreads();   // barrier 2: zpart ready

  // ---- phase 4+5: combine chunks + LN stats, per 32-row half ----
  #pragma unroll
  for (int h = 0; h < 2; ++h) {
    const int row = h*32 + (tid >> 3), w = tid & 7;
    const int slot = (w < 3) ? 0 : (w - 2);
    const int sm = (w == 0) ? 4 : (w == 1) ? 2 : (w == 2) ? 1 : 0;
    float z = 0.f;
    #pragma unroll
    for (int ch = 0; ch < 8; ++ch) {
      float v = zpart[(ch*64 + row)*9 + slot];
      z += (ch & sm) ? -v : v;
    }
    zrow[row*8 + w] = z;
    // same wave wrote all 8 slots of this row -> in-order DS, read back
    f32x4 zlo = *(const f32x4*)&zrow[row*8];
    f32x4 zhi = *(const f32x4*)&zrow[row*8 + 4];
    float zj[8] = {zlo[0], zlo[1], zlo[2], zlo[3], zhi[0], zhi[1], zhi[2], zhi[3]};
    float qi = statsL[8 + w];
    #pragma unroll
    for (int j = 0; j < 8; ++j) qi += statsL[16 + w*8 + j] * zj[j];
    float e2p = zj[w] * qi;
    float mup = statsL[w] * zj[w];
    e2p += shxor(e2p, 1); e2p += shxor(e2p, 2); e2p += shxor(e2p, 4);
    mup += shxor(mup, 1); mup += shxor(mup, 2); mup += shxor(mup, 4);
    if (w == 0) {
      float mu = mup + statsL[80];
      float e2 = e2p + statsL[81];
      float var = e2 - mu*mu;
      musig[row*2]     = mu;
      musig[row*2 + 1] = rsqrtf(fmaxf(var, 0.f) + 1e-5f);
    }
  }
  // no barrier: phase 6 reads only this wave's zrow/musig rows

  // ---- phase 6: FC + LN + exact GELU (16 rows per wave, wave-matched) ----
  #pragma unroll
  for (int h = 0; h < 2; ++h) {
    #pragma unroll
    for (int rr = 0; rr < 8; ++rr) {
      const int row = h*32 + wid*8 + rr;
      const int gr = r0 + row;
      float hv = biasL[lane];
      #pragma unroll
      for (int i = 0; i < 8; ++i) hv = fmaf(zrow[row*8 + i], Wl[i*64 + lane], hv);
      float hn = (hv - musig[row*2]) * musig[row*2 + 1] * gammaL[lane] + betaL[lane];
      float ge = 0.5f * hn * (1.f + erff(hn * 0.70710678118654752f));
      if (gr < B) out[gr*64 + lane] = ge;
    }
  }
}

extern "C" void kernel_launch(void* const* d_in, const int* in_sizes, int n_in,
                              void* d_out, int out_size, void* d_ws, size_t ws_size,
                              hipStream_t stream) {
  const float* pca   = (const float*)d_in[0];
  const float* qw    = (const float*)d_in[1];
  const float* Wm    = (const float*)d_in[2];
  const float* bias  = (const float*)d_in[3];
  const float* gamma = (const float*)d_in[4];
  const float* beta  = (const float*)d_in[5];
  float* out = (float*)d_out;

  _Float16* Bfrag = (_Float16*)d_ws;                   // 512*256*2 = 256 KiB
  float* stats = (float*)((char*)d_ws + 512*256*2);    // 82 floats

  int B = in_sizes[0] / 8;

  hipLaunchKernelGGL(qsb_prep, dim3(257), dim3(64), 0, stream, qw, Wm, bias, Bfrag, stats);
  int blocks = (B + 63) / 64;
  hipLaunchKernelGGL(qsb_main, dim3(blocks), dim3(256), 0, stream,
                     pca, Bfrag, stats, Wm, bias, gamma, beta, out, B);
}